// Round 1
// baseline (753.610 us; speedup 1.0000x reference)
//
#include <hip/hip_runtime.h>

#define HW 409600
#define NCH 12

// workspace layout (bytes)
#define OFF_TACC 0                      // 16*3 floats
#define OFF_KACC 256                    // 80*3 floats
#define OFF_POS  2048                   // 16 u32
#define OFF_NEG  2112
#define OFF_B1   2176
#define OFF_KREM 2240
#define OFF_FB   2304
#define OFF_THR  2368                   // 16 f32
#define OFF_HIST 8192
#define HIST_BYTES (16u*65536u*4u)      // 4 MiB
#define OFF_MASK (OFF_HIST + HIST_BYTES)
// mask bytes: 16*HW = 6.25 MiB; total ws use ~10.3 MiB

__device__ __forceinline__ unsigned flipkey(float x){
  unsigned b = __float_as_uint(x);
  return (b & 0x80000000u) ? ~b : (b | 0x80000000u);   // monotone float->uint
}
__device__ __forceinline__ float unflip(unsigned u){
  unsigned b = (u & 0x80000000u) ? (u ^ 0x80000000u) : ~u;
  return __uint_as_float(b);
}

// K1: counts + mask bytes + MSB16 histogram of negative texts scores
__global__ __launch_bounds__(256) void k_hist1(
    const float* __restrict__ outputs, const float* __restrict__ labels,
    const float* __restrict__ tmask, unsigned char* __restrict__ maskb,
    unsigned* __restrict__ hist, unsigned* __restrict__ posA, unsigned* __restrict__ negA)
{
  int img = blockIdx.x / 400;        // img = ci*8 + bi
  int blk = blockIdx.x % 400;
  int ci = img >> 3, bi = img & 7;
  int px = blk*1024 + (int)threadIdx.x*4;
  const float* tp = outputs + (size_t)(bi*NCH + ci*6 + 5)*HW;
  const float* gp = labels  + (size_t)(bi*NCH + ci*6 + 5)*HW;
  const float* mp = tmask   + (size_t)bi*HW;
  float4 tv = *(const float4*)(tp+px);
  float4 gv = *(const float4*)(gp+px);
  float4 mv = *(const float4*)(mp+px);
  float tt[4]={tv.x,tv.y,tv.z,tv.w};
  float gg[4]={gv.x,gv.y,gv.z,gv.w};
  float mm[4]={mv.x,mv.y,mv.z,mv.w};
  unsigned* h = hist + (size_t)img*65536u;
  unsigned pos=0, neg=0;
  unsigned char mb[4];
  #pragma unroll
  for (int c=0;c<4;c++){
    bool isneg = (gg[c] <= 0.5f);
    bool tpos  = (mm[c] > 0.5f);
    pos += (unsigned)((!isneg) && tpos);
    neg += (unsigned)isneg;
    mb[c] = (unsigned char)((((tt[c] > 0.0f) && tpos) ? 1u : 0u) | (tpos ? 2u : 0u));
    if (isneg) atomicAdd(&h[flipkey(tt[c]) >> 16], 1u);
  }
  uchar4 mq; mq.x=mb[0]; mq.y=mb[1]; mq.z=mb[2]; mq.w=mb[3];
  *(uchar4*)(maskb + (size_t)img*HW + px) = mq;

  #pragma unroll
  for (int o=32;o;o>>=1){ pos += __shfl_down(pos,o,64); neg += __shfl_down(neg,o,64); }
  __shared__ unsigned sp[4], sn[4];
  int wv = threadIdx.x >> 6, ln = threadIdx.x & 63;
  if (ln==0){ sp[wv]=pos; sn[wv]=neg; }
  __syncthreads();
  if (threadIdx.x==0){
    atomicAdd(&posA[img], sp[0]+sp[1]+sp[2]+sp[3]);
    atomicAdd(&negA[img], sn[0]+sn[1]+sn[2]+sn[3]);
  }
}

// K2: descending scan of MSB16 histogram -> bin b1 + residual rank
__global__ __launch_bounds__(256) void k_scan1(
    const unsigned* __restrict__ hist, const unsigned* __restrict__ posA,
    const unsigned* __restrict__ negA, unsigned* __restrict__ b1A,
    unsigned* __restrict__ kremA, unsigned* __restrict__ fbA)
{
  int img = blockIdx.x; int t = threadIdx.x;
  unsigned pos = posA[img], negt = negA[img];
  unsigned p3 = pos*3u;
  unsigned negnum = (p3 < negt) ? p3 : negt;
  if (pos==0u || negnum==0u){
    if (t==0){ fbA[img]=1u; b1A[img]=0u; kremA[img]=1u; }
    return;
  }
  if (t==0) fbA[img]=0u;
  const unsigned* h = hist + (size_t)img*65536u;
  unsigned s=0;
  for (int j=0;j<256;j++) s += h[t*256+j];
  __shared__ unsigned cs[256];
  __shared__ unsigned shc, shk;
  cs[t]=s; __syncthreads();
  if (t==0){
    unsigned k=negnum, cum=0, ch=0, kin=k;
    for (int c=255;c>=0;c--){
      if (cum + cs[c] >= k){ ch=(unsigned)c; kin=k-cum; break; }
      cum += cs[c];
    }
    shc=ch; shk=kin;
  }
  __syncthreads();
  __shared__ unsigned bv[256];
  bv[t] = h[shc*256u + (unsigned)t];
  __syncthreads();
  if (t==0){
    unsigned cum=0, kin=shk, bn=0, kr=1;
    for (int x=255;x>=0;x--){
      cum += bv[x];
      if (cum >= kin){ bn=(unsigned)x; kr = kin - (cum - bv[x]); break; }
    }
    b1A[img] = shc*256u + bn;
    kremA[img] = kr;
  }
}

// K3: LSB16 histogram among negatives whose MSB16 == b1
__global__ __launch_bounds__(256) void k_hist2(
    const float* __restrict__ outputs, const float* __restrict__ labels,
    const unsigned* __restrict__ b1A, const unsigned* __restrict__ fbA,
    unsigned* __restrict__ hist)
{
  int img = blockIdx.x / 400;
  if (fbA[img]) return;
  int blk = blockIdx.x % 400;
  int ci = img>>3, bi = img&7;
  unsigned b1 = b1A[img];
  int px = blk*1024 + (int)threadIdx.x*4;
  const float* tp = outputs + (size_t)(bi*NCH + ci*6 + 5)*HW;
  const float* gp = labels  + (size_t)(bi*NCH + ci*6 + 5)*HW;
  float4 tv = *(const float4*)(tp+px);
  float4 gv = *(const float4*)(gp+px);
  float tt[4]={tv.x,tv.y,tv.z,tv.w};
  float gg[4]={gv.x,gv.y,gv.z,gv.w};
  unsigned* h = hist + (size_t)img*65536u;
  #pragma unroll
  for (int c=0;c<4;c++){
    if (gg[c] <= 0.5f){
      unsigned key = flipkey(tt[c]);
      if ((key>>16) == b1) atomicAdd(&h[key & 0xFFFFu], 1u);
    }
  }
}

// K4: descending scan of LSB16 histogram -> exact 32-bit key -> threshold float
__global__ __launch_bounds__(256) void k_scan2(
    const unsigned* __restrict__ hist, const unsigned* __restrict__ b1A,
    const unsigned* __restrict__ kremA, const unsigned* __restrict__ fbA,
    float* __restrict__ thrA)
{
  int img = blockIdx.x; int t = threadIdx.x;
  if (fbA[img]){ if (t==0) thrA[img]=0.0f; return; }
  const unsigned* h = hist + (size_t)img*65536u;
  unsigned s=0;
  for (int j=0;j<256;j++) s += h[t*256+j];
  __shared__ unsigned cs[256]; __shared__ unsigned shc, shk;
  cs[t]=s; __syncthreads();
  if (t==0){
    unsigned k=kremA[img], cum=0, ch=0, kin=k;
    for (int c=255;c>=0;c--){ if (cum+cs[c]>=k){ ch=(unsigned)c; kin=k-cum; break;} cum+=cs[c]; }
    shc=ch; shk=kin;
  }
  __syncthreads();
  __shared__ unsigned bv[256];
  bv[t]=h[shc*256u+(unsigned)t]; __syncthreads();
  if (t==0){
    unsigned cum=0, bn=0;
    for (int x=255;x>=0;x--){ cum+=bv[x]; if (cum>=shk){ bn=(unsigned)x; break; } }
    unsigned key = (b1A[img]<<16) | (shc*256u + bn);
    thrA[img] = unflip(key);
  }
}

// K5: dice sums for all 96 (class,batch,channel) images
__global__ __launch_bounds__(256) void k_dice(
    const float* __restrict__ outputs, const float* __restrict__ labels,
    const float* __restrict__ tmask, const unsigned char* __restrict__ maskb,
    const unsigned* __restrict__ fbA, const float* __restrict__ thrA,
    float* __restrict__ tacc, float* __restrict__ kacc)
{
  int cimg = blockIdx.x / 100;      // (img)*6 + j
  int blk  = blockIdx.x % 100;
  int img = cimg / 6, j = cimg % 6;
  int ci = img>>3, bi = img&7;
  const float* pp_ = outputs + (size_t)(bi*NCH + ci*6 + j)*HW;
  const float* gp  = labels  + (size_t)(bi*NCH + ci*6 + j)*HW;
  const unsigned char* mk = maskb + (size_t)img*HW;
  const float* tmp = tmask + (size_t)bi*HW;
  bool istext = (j==5);
  bool fb = istext && (fbA[img] != 0u);
  float thr = istext ? thrA[img] : 0.0f;
  float sa=0.f, sb=0.f, sc=0.f;
  #pragma unroll
  for (int it=0; it<4; it++){
    int px = blk*4096 + it*1024 + (int)threadIdx.x*4;
    float4 pv = *(const float4*)(pp_+px);
    float4 gv = *(const float4*)(gp+px);
    uchar4 mq = *(const uchar4*)(mk+px);
    float pa[4]={pv.x,pv.y,pv.z,pv.w};
    float ga[4]={gv.x,gv.y,gv.z,gv.w};
    unsigned char ma[4]={mq.x,mq.y,mq.z,mq.w};
    float ta[4]={0.f,0.f,0.f,0.f};
    if (fb){ float4 tv=*(const float4*)(tmp+px); ta[0]=tv.x;ta[1]=tv.y;ta[2]=tv.z;ta[3]=tv.w; }
    #pragma unroll
    for (int c=0;c<4;c++){
      float m;
      if (istext){
        if (fb) m = ta[c];
        else    m = (((pa[c] >= thr) || (ga[c] > 0.5f)) && (ma[c] & 2)) ? 1.0f : 0.0f;
      } else {
        m = (ma[c] & 1) ? 1.0f : 0.0f;
      }
      float p = __fdividef(1.0f, 1.0f + __expf(-pa[c])) * m;
      float tt = ga[c]*m;
      sa += p*tt; sb += p*p; sc += tt*tt;
    }
  }
  #pragma unroll
  for (int o=32;o;o>>=1){
    sa += __shfl_down(sa,o,64); sb += __shfl_down(sb,o,64); sc += __shfl_down(sc,o,64);
  }
  __shared__ float ra[4], rb[4], rc[4];
  int wv = threadIdx.x>>6, ln = threadIdx.x&63;
  if (ln==0){ ra[wv]=sa; rb[wv]=sb; rc[wv]=sc; }
  __syncthreads();
  if (threadIdx.x==0){
    float A=ra[0]+ra[1]+ra[2]+ra[3];
    float Bs=rb[0]+rb[1]+rb[2]+rb[3];
    float Cs=rc[0]+rc[1]+rc[2]+rc[3];
    float* acc = istext ? (tacc + img*3) : (kacc + (img*5 + j)*3);
    atomicAdd(acc+0, A); atomicAdd(acc+1, Bs); atomicAdd(acc+2, Cs);
  }
}

// K6: finalize 3 outputs
__global__ void k_final(const float* __restrict__ tacc, const float* __restrict__ kacc,
                        float* __restrict__ out)
{
  if (blockIdx.x==0 && threadIdx.x==0){
    const float EPSF = 1e-4f;
    float ltA[2], lkA[2];
    for (int i=0;i<2;i++){
      float lt=0.f;
      for (int b=0;b<8;b++){
        int img=i*8+b;
        float a=tacc[img*3], p2=tacc[img*3+1]+EPSF, t2=tacc[img*3+2]+EPSF;
        lt += 1.f - 2.f*a/(p2+t2);
      }
      lt *= 0.125f;
      float lk=0.f;
      for (int b=0;b<8;b++) for (int k=0;k<5;k++){
        int idx=((i*8+b)*5+k)*3;
        float a=kacc[idx], p2=kacc[idx+1]+EPSF, t2=kacc[idx+2]+EPSF;
        lk += 1.f - 2.f*a/(p2+t2);
      }
      lk /= 40.f;
      ltA[i]=lt; lkA[i]=lk;
    }
    float l0 = 0.7f*ltA[0] + 0.3f*lkA[0];
    float l1 = 0.7f*ltA[1] + 0.3f*lkA[1];
    out[0]=0.5f*(l0+l1);
    out[1]=0.5f*(ltA[0]+ltA[1]);
    out[2]=0.5f*(lkA[0]+lkA[1]);
  }
}

extern "C" void kernel_launch(void* const* d_in, const int* in_sizes, int n_in,
                              void* d_out, int out_size, void* d_ws, size_t ws_size,
                              hipStream_t stream)
{
  const float* outputs = (const float*)d_in[0];
  const float* labels  = (const float*)d_in[1];
  const float* tmask   = (const float*)d_in[2];
  float* out = (float*)d_out;
  char* ws = (char*)d_ws;
  float* tacc    = (float*)(ws + OFF_TACC);
  float* kacc    = (float*)(ws + OFF_KACC);
  unsigned* posA = (unsigned*)(ws + OFF_POS);
  unsigned* negA = (unsigned*)(ws + OFF_NEG);
  unsigned* b1A  = (unsigned*)(ws + OFF_B1);
  unsigned* kremA= (unsigned*)(ws + OFF_KREM);
  unsigned* fbA  = (unsigned*)(ws + OFF_FB);
  float* thrA    = (float*)(ws + OFF_THR);
  unsigned* hist = (unsigned*)(ws + OFF_HIST);
  unsigned char* maskb = (unsigned char*)(ws + OFF_MASK);

  hipMemsetAsync(ws, 0, OFF_HIST + HIST_BYTES, stream);          // accs + meta + hist
  k_hist1<<<6400,256,0,stream>>>(outputs, labels, tmask, maskb, hist, posA, negA);
  k_scan1<<<16,256,0,stream>>>(hist, posA, negA, b1A, kremA, fbA);
  hipMemsetAsync(ws + OFF_HIST, 0, HIST_BYTES, stream);          // reuse hist buffer
  k_hist2<<<6400,256,0,stream>>>(outputs, labels, b1A, fbA, hist);
  k_scan2<<<16,256,0,stream>>>(hist, b1A, kremA, fbA, thrA);
  k_dice<<<9600,256,0,stream>>>(outputs, labels, tmask, maskb, fbA, thrA, tacc, kacc);
  k_final<<<1,64,0,stream>>>(tacc, kacc, out);
}

// Round 2
// 436.396 us; speedup vs baseline: 1.7269x; 1.7269x over previous
//
#include <hip/hip_runtime.h>

#define HW 409600
#define NCH 12

// workspace layout (bytes)
#define OFF_TACC 0                      // 16*3 floats
#define OFF_KACC 256                    // 80*3 floats
#define OFF_POS   2048                  // 16 u32 each
#define OFF_NEG   2112
#define OFF_SEL1  2176
#define OFF_KREM1 2240
#define OFF_SEL2  2304
#define OFF_KREM2 2368
#define OFF_FB    2432
#define OFF_THR   2496                  // 16 f32
#define OFF_HA    4096                  // 16*2048 u32 = 128 KiB
#define OFF_HB    (OFF_HA + 16*2048*4)  // 128 KiB
#define OFF_HC    (OFF_HB + 16*2048*4)  // 16*1024 u32 = 64 KiB
#define OFF_META_END (OFF_HC + 16*1024*4)
#define OFF_MASK  ((OFF_META_END + 255) & ~255)
// mask bytes: 16*HW = 6.25 MiB

__device__ __forceinline__ unsigned flipkey(float x){
  unsigned b = __float_as_uint(x);
  return (b & 0x80000000u) ? ~b : (b | 0x80000000u);   // monotone float->uint
}
__device__ __forceinline__ float unflip(unsigned u){
  unsigned b = (u & 0x80000000u) ? (u ^ 0x80000000u) : ~u;
  return __uint_as_float(b);
}

// K1: counts + mask bytes (bit0=selk, bit1=tm>0.5, bit2=neg) + LDS hist of key[31:21]
__global__ __launch_bounds__(256) void k_prep(
    const float* __restrict__ outputs, const float* __restrict__ labels,
    const float* __restrict__ tmask, unsigned char* __restrict__ maskb,
    unsigned* __restrict__ histA, unsigned* __restrict__ posA, unsigned* __restrict__ negA)
{
  int img = blockIdx.x / 50;         // img = ci*8 + bi
  int blk = blockIdx.x % 50;
  int ci = img >> 3, bi = img & 7;
  const float* tp = outputs + (size_t)(bi*NCH + ci*6 + 5)*HW;
  const float* gp = labels  + (size_t)(bi*NCH + ci*6 + 5)*HW;
  const float* mp = tmask   + (size_t)bi*HW;

  __shared__ unsigned lh[2048];
  for (int j=threadIdx.x; j<2048; j+=256) lh[j]=0u;
  __syncthreads();

  unsigned pos=0, neg=0;
  #pragma unroll
  for (int it=0; it<8; it++){
    int px = blk*8192 + it*1024 + (int)threadIdx.x*4;
    float4 tv = *(const float4*)(tp+px);
    float4 gv = *(const float4*)(gp+px);
    float4 mv = *(const float4*)(mp+px);
    float tt[4]={tv.x,tv.y,tv.z,tv.w};
    float gg[4]={gv.x,gv.y,gv.z,gv.w};
    float mm[4]={mv.x,mv.y,mv.z,mv.w};
    unsigned char mb[4];
    #pragma unroll
    for (int c=0;c<4;c++){
      bool isneg = (gg[c] <= 0.5f);
      bool tpos  = (mm[c] > 0.5f);
      pos += (unsigned)((!isneg) && tpos);
      neg += (unsigned)isneg;
      mb[c] = (unsigned char)((((tt[c] > 0.0f) && tpos) ? 1u : 0u) |
                              (tpos ? 2u : 0u) | (isneg ? 4u : 0u));
      if (isneg) atomicAdd(&lh[flipkey(tt[c]) >> 21], 1u);
    }
    uchar4 mq; mq.x=mb[0]; mq.y=mb[1]; mq.z=mb[2]; mq.w=mb[3];
    *(uchar4*)(maskb + (size_t)img*HW + px) = mq;
  }
  #pragma unroll
  for (int o=32;o;o>>=1){ pos += __shfl_down(pos,o,64); neg += __shfl_down(neg,o,64); }
  __shared__ unsigned sp[4], sn[4];
  int wv = threadIdx.x >> 6, ln = threadIdx.x & 63;
  if (ln==0){ sp[wv]=pos; sn[wv]=neg; }
  __syncthreads();
  if (threadIdx.x==0){
    atomicAdd(&posA[img], sp[0]+sp[1]+sp[2]+sp[3]);
    atomicAdd(&negA[img], sn[0]+sn[1]+sn[2]+sn[3]);
  }
  unsigned* gh = histA + (size_t)img*2048u;
  for (int j=threadIdx.x; j<2048; j+=256){
    unsigned v = lh[j];
    if (v) atomicAdd(&gh[j], v);
  }
}

// generic descending-rank scan over NB bins (NB = 2048 or 1024), 256 threads
template<int NB>
__device__ void scan_desc(const unsigned* h, unsigned k, unsigned* selOut, unsigned* kremOut)
{
  const int PER = NB/256;
  int t = threadIdx.x;
  unsigned s=0;
  #pragma unroll
  for (int j=0;j<PER;j++) s += h[t*PER+j];
  __shared__ unsigned cs[256];
  cs[t]=s; __syncthreads();
  if (t==0){
    unsigned cum=0, ch=0, kin=k;
    for (int c=255;c>=0;c--){
      if (cum + cs[c] >= k){ ch=(unsigned)c; kin=k-cum; break; }
      cum += cs[c];
    }
    unsigned cum2=0, sel=ch*PER, kr=1;
    for (int x=PER-1;x>=0;x--){
      unsigned v = h[ch*PER+x];
      cum2 += v;
      if (cum2 >= kin){ sel=ch*PER+(unsigned)x; kr = kin - (cum2 - v); break; }
    }
    *selOut = sel; *kremOut = kr;
  }
}

// K2: pass-a scan -> sel1 (11 bits) + residual rank; fallback detect
__global__ __launch_bounds__(256) void k_scan_a(
    const unsigned* __restrict__ histA, const unsigned* __restrict__ posA,
    const unsigned* __restrict__ negA, unsigned* __restrict__ sel1A,
    unsigned* __restrict__ krem1A, unsigned* __restrict__ fbA)
{
  int img = blockIdx.x;
  unsigned pos = posA[img], negt = negA[img];
  unsigned p3 = pos*3u;
  unsigned negnum = (p3 < negt) ? p3 : negt;
  if (pos==0u || negnum==0u){
    if (threadIdx.x==0){ fbA[img]=1u; sel1A[img]=0u; krem1A[img]=1u; }
    return;
  }
  if (threadIdx.x==0) fbA[img]=0u;
  scan_desc<2048>(histA + (size_t)img*2048u, negnum, &sel1A[img], &krem1A[img]);
}

// K3: pass-b hist: bits [20:10] of negatives whose key[31:21]==sel1
__global__ __launch_bounds__(256) void k_histb(
    const float* __restrict__ outputs, const unsigned char* __restrict__ maskb,
    const unsigned* __restrict__ sel1A, const unsigned* __restrict__ fbA,
    unsigned* __restrict__ histB)
{
  int img = blockIdx.x / 50;
  if (fbA[img]) return;
  int blk = blockIdx.x % 50;
  int ci = img>>3, bi = img&7;
  unsigned sel1 = sel1A[img];
  const float* tp = outputs + (size_t)(bi*NCH + ci*6 + 5)*HW;
  const unsigned char* mk = maskb + (size_t)img*HW;

  __shared__ unsigned lh[2048];
  for (int j=threadIdx.x; j<2048; j+=256) lh[j]=0u;
  __syncthreads();

  #pragma unroll
  for (int it=0; it<8; it++){
    int px = blk*8192 + it*1024 + (int)threadIdx.x*4;
    float4 tv = *(const float4*)(tp+px);
    uchar4 mq = *(const uchar4*)(mk+px);
    float tt[4]={tv.x,tv.y,tv.z,tv.w};
    unsigned char ma[4]={mq.x,mq.y,mq.z,mq.w};
    #pragma unroll
    for (int c=0;c<4;c++){
      if (ma[c] & 4){
        unsigned key = flipkey(tt[c]);
        if ((key>>21) == sel1) atomicAdd(&lh[(key>>10) & 0x7FFu], 1u);
      }
    }
  }
  __syncthreads();
  unsigned* gh = histB + (size_t)img*2048u;
  for (int j=threadIdx.x; j<2048; j+=256){
    unsigned v = lh[j];
    if (v) atomicAdd(&gh[j], v);
  }
}

// K4: pass-b scan -> sel2 + residual
__global__ __launch_bounds__(256) void k_scan_b(
    const unsigned* __restrict__ histB, const unsigned* __restrict__ krem1A,
    const unsigned* __restrict__ fbA, unsigned* __restrict__ sel2A,
    unsigned* __restrict__ krem2A)
{
  int img = blockIdx.x;
  if (fbA[img]){ if (threadIdx.x==0){ sel2A[img]=0u; krem2A[img]=1u; } return; }
  scan_desc<2048>(histB + (size_t)img*2048u, krem1A[img], &sel2A[img], &krem2A[img]);
}

// K5: pass-c hist: bits [9:0] of negatives whose key[31:10]==(sel1<<11|sel2)
__global__ __launch_bounds__(256) void k_histc(
    const float* __restrict__ outputs, const unsigned char* __restrict__ maskb,
    const unsigned* __restrict__ sel1A, const unsigned* __restrict__ sel2A,
    const unsigned* __restrict__ fbA, unsigned* __restrict__ histC)
{
  int img = blockIdx.x / 50;
  if (fbA[img]) return;
  int blk = blockIdx.x % 50;
  int ci = img>>3, bi = img&7;
  unsigned p22 = (sel1A[img]<<11) | sel2A[img];
  const float* tp = outputs + (size_t)(bi*NCH + ci*6 + 5)*HW;
  const unsigned char* mk = maskb + (size_t)img*HW;

  __shared__ unsigned lh[1024];
  for (int j=threadIdx.x; j<1024; j+=256) lh[j]=0u;
  __syncthreads();

  #pragma unroll
  for (int it=0; it<8; it++){
    int px = blk*8192 + it*1024 + (int)threadIdx.x*4;
    float4 tv = *(const float4*)(tp+px);
    uchar4 mq = *(const uchar4*)(mk+px);
    float tt[4]={tv.x,tv.y,tv.z,tv.w};
    unsigned char ma[4]={mq.x,mq.y,mq.z,mq.w};
    #pragma unroll
    for (int c=0;c<4;c++){
      if (ma[c] & 4){
        unsigned key = flipkey(tt[c]);
        if ((key>>10) == p22) atomicAdd(&lh[key & 0x3FFu], 1u);
      }
    }
  }
  __syncthreads();
  unsigned* gh = histC + (size_t)img*1024u;
  for (int j=threadIdx.x; j<1024; j+=256){
    unsigned v = lh[j];
    if (v) atomicAdd(&gh[j], v);
  }
}

// K6: pass-c scan -> exact 32-bit key -> threshold float
__global__ __launch_bounds__(256) void k_scan_c(
    const unsigned* __restrict__ histC, const unsigned* __restrict__ sel1A,
    const unsigned* __restrict__ sel2A, const unsigned* __restrict__ krem2A,
    const unsigned* __restrict__ fbA, float* __restrict__ thrA)
{
  int img = blockIdx.x;
  if (fbA[img]){ if (threadIdx.x==0) thrA[img]=0.0f; return; }
  __shared__ unsigned sel3, kr;
  scan_desc<1024>(histC + (size_t)img*1024u, krem2A[img], &sel3, &kr);
  __syncthreads();
  if (threadIdx.x==0){
    unsigned key = (sel1A[img]<<21) | (sel2A[img]<<10) | sel3;
    thrA[img] = unflip(key);
  }
}

// K7: dice sums for all 96 (class,batch,channel) images
__global__ __launch_bounds__(256) void k_dice(
    const float* __restrict__ outputs, const float* __restrict__ labels,
    const float* __restrict__ tmask, const unsigned char* __restrict__ maskb,
    const unsigned* __restrict__ fbA, const float* __restrict__ thrA,
    float* __restrict__ tacc, float* __restrict__ kacc)
{
  int cimg = blockIdx.x / 100;      // (img)*6 + j
  int blk  = blockIdx.x % 100;
  int img = cimg / 6, j = cimg % 6;
  int ci = img>>3, bi = img&7;
  const float* pp_ = outputs + (size_t)(bi*NCH + ci*6 + j)*HW;
  const float* gp  = labels  + (size_t)(bi*NCH + ci*6 + j)*HW;
  const unsigned char* mk = maskb + (size_t)img*HW;
  const float* tmp = tmask + (size_t)bi*HW;
  bool istext = (j==5);
  bool fb = istext && (fbA[img] != 0u);
  float thr = istext ? thrA[img] : 0.0f;
  float sa=0.f, sb=0.f, sc=0.f;
  #pragma unroll
  for (int it=0; it<4; it++){
    int px = blk*4096 + it*1024 + (int)threadIdx.x*4;
    float4 pv = *(const float4*)(pp_+px);
    float4 gv = *(const float4*)(gp+px);
    uchar4 mq = *(const uchar4*)(mk+px);
    float pa[4]={pv.x,pv.y,pv.z,pv.w};
    float ga[4]={gv.x,gv.y,gv.z,gv.w};
    unsigned char ma[4]={mq.x,mq.y,mq.z,mq.w};
    float ta[4]={0.f,0.f,0.f,0.f};
    if (fb){ float4 tv=*(const float4*)(tmp+px); ta[0]=tv.x;ta[1]=tv.y;ta[2]=tv.z;ta[3]=tv.w; }
    #pragma unroll
    for (int c=0;c<4;c++){
      float m;
      if (istext){
        if (fb) m = ta[c];
        else    m = (((pa[c] >= thr) || (ga[c] > 0.5f)) && (ma[c] & 2)) ? 1.0f : 0.0f;
      } else {
        m = (ma[c] & 1) ? 1.0f : 0.0f;
      }
      float p = __fdividef(1.0f, 1.0f + __expf(-pa[c])) * m;
      float tt = ga[c]*m;
      sa += p*tt; sb += p*p; sc += tt*tt;
    }
  }
  #pragma unroll
  for (int o=32;o;o>>=1){
    sa += __shfl_down(sa,o,64); sb += __shfl_down(sb,o,64); sc += __shfl_down(sc,o,64);
  }
  __shared__ float ra[4], rb[4], rc[4];
  int wv = threadIdx.x>>6, ln = threadIdx.x&63;
  if (ln==0){ ra[wv]=sa; rb[wv]=sb; rc[wv]=sc; }
  __syncthreads();
  if (threadIdx.x==0){
    float A=ra[0]+ra[1]+ra[2]+ra[3];
    float Bs=rb[0]+rb[1]+rb[2]+rb[3];
    float Cs=rc[0]+rc[1]+rc[2]+rc[3];
    float* acc = istext ? (tacc + img*3) : (kacc + (img*5 + j)*3);
    atomicAdd(acc+0, A); atomicAdd(acc+1, Bs); atomicAdd(acc+2, Cs);
  }
}

// K8: finalize 3 outputs
__global__ void k_final(const float* __restrict__ tacc, const float* __restrict__ kacc,
                        float* __restrict__ out)
{
  if (blockIdx.x==0 && threadIdx.x==0){
    const float EPSF = 1e-4f;
    float ltA[2], lkA[2];
    for (int i=0;i<2;i++){
      float lt=0.f;
      for (int b=0;b<8;b++){
        int img=i*8+b;
        float a=tacc[img*3], p2=tacc[img*3+1]+EPSF, t2=tacc[img*3+2]+EPSF;
        lt += 1.f - 2.f*a/(p2+t2);
      }
      lt *= 0.125f;
      float lk=0.f;
      for (int b=0;b<8;b++) for (int k=0;k<5;k++){
        int idx=((i*8+b)*5+k)*3;
        float a=kacc[idx], p2=kacc[idx+1]+EPSF, t2=kacc[idx+2]+EPSF;
        lk += 1.f - 2.f*a/(p2+t2);
      }
      lk /= 40.f;
      ltA[i]=lt; lkA[i]=lk;
    }
    float l0 = 0.7f*ltA[0] + 0.3f*lkA[0];
    float l1 = 0.7f*ltA[1] + 0.3f*lkA[1];
    out[0]=0.5f*(l0+l1);
    out[1]=0.5f*(ltA[0]+ltA[1]);
    out[2]=0.5f*(lkA[0]+lkA[1]);
  }
}

extern "C" void kernel_launch(void* const* d_in, const int* in_sizes, int n_in,
                              void* d_out, int out_size, void* d_ws, size_t ws_size,
                              hipStream_t stream)
{
  const float* outputs = (const float*)d_in[0];
  const float* labels  = (const float*)d_in[1];
  const float* tmask   = (const float*)d_in[2];
  float* out = (float*)d_out;
  char* ws = (char*)d_ws;
  float* tacc     = (float*)(ws + OFF_TACC);
  float* kacc     = (float*)(ws + OFF_KACC);
  unsigned* posA  = (unsigned*)(ws + OFF_POS);
  unsigned* negA  = (unsigned*)(ws + OFF_NEG);
  unsigned* sel1A = (unsigned*)(ws + OFF_SEL1);
  unsigned* krem1A= (unsigned*)(ws + OFF_KREM1);
  unsigned* sel2A = (unsigned*)(ws + OFF_SEL2);
  unsigned* krem2A= (unsigned*)(ws + OFF_KREM2);
  unsigned* fbA   = (unsigned*)(ws + OFF_FB);
  float* thrA     = (float*)(ws + OFF_THR);
  unsigned* histA = (unsigned*)(ws + OFF_HA);
  unsigned* histB = (unsigned*)(ws + OFF_HB);
  unsigned* histC = (unsigned*)(ws + OFF_HC);
  unsigned char* maskb = (unsigned char*)(ws + OFF_MASK);

  hipMemsetAsync(ws, 0, OFF_META_END, stream);   // accs + meta + all hists (~324 KiB)
  k_prep  <<<800,256,0,stream>>>(outputs, labels, tmask, maskb, histA, posA, negA);
  k_scan_a<<<16,256,0,stream>>>(histA, posA, negA, sel1A, krem1A, fbA);
  k_histb <<<800,256,0,stream>>>(outputs, maskb, sel1A, fbA, histB);
  k_scan_b<<<16,256,0,stream>>>(histB, krem1A, fbA, sel2A, krem2A);
  k_histc <<<800,256,0,stream>>>(outputs, maskb, sel1A, sel2A, fbA, histC);
  k_scan_c<<<16,256,0,stream>>>(histC, sel1A, sel2A, krem2A, fbA, thrA);
  k_dice  <<<9600,256,0,stream>>>(outputs, labels, tmask, maskb, fbA, thrA, tacc, kacc);
  k_final <<<1,64,0,stream>>>(tacc, kacc, out);
}

// Round 3
// 369.048 us; speedup vs baseline: 2.0420x; 1.1825x over previous
//
#include <hip/hip_runtime.h>

#define HW 409600
#define NCH 12

// workspace layout (bytes)
#define OFF_TACC   0                     // 16*3 floats
#define OFF_KACC   256                   // 80*3 floats
#define OFF_POS    2048                  // 16 u32 each slot below
#define OFF_NEG    2112
#define OFF_DONE   2176
#define OFF_FB     2240
#define OFF_NEGNUM 2304
#define OFF_MAXNK  2368
#define OFF_SEL1   2432
#define OFF_KREM1  2496
#define OFF_SEL2   2560
#define OFF_KREM2  2624
#define OFF_THR    2688                  // 16 f32
#define OFF_HA     4096                  // 16*2048 u32 = 128 KiB
#define OFF_HB     (OFF_HA + 16*2048*4)
#define OFF_HC     (OFF_HB + 16*2048*4)  // 16*1024 u32 = 64 KiB
#define OFF_META_END (OFF_HC + 16*1024*4)
#define OFF_MASK   ((OFF_META_END + 255) & ~255)

__device__ __forceinline__ unsigned flipkey(float x){
  unsigned b = __float_as_uint(x);
  return (b & 0x80000000u) ? ~b : (b | 0x80000000u);   // monotone float->uint
}
__device__ __forceinline__ float unflip(unsigned u){
  unsigned b = (u & 0x80000000u) ? (u ^ 0x80000000u) : ~u;
  return __uint_as_float(b);
}

// K1: counts + mask bytes (bit0=selk, bit1=tm>0.5, bit2=neg) + min negative key.
// NO histogram here (no LDS atomics) — generic radix path runs later only if needed.
__global__ __launch_bounds__(256) void k_count(
    const float* __restrict__ outputs, const float* __restrict__ labels,
    const float* __restrict__ tmask, unsigned char* __restrict__ maskb,
    unsigned* __restrict__ posA, unsigned* __restrict__ negA,
    unsigned* __restrict__ maxnkA)
{
  int img = blockIdx.x / 100;        // img = ci*8 + bi
  int blk = blockIdx.x % 100;
  int ci = img >> 3, bi = img & 7;
  const float* tp = outputs + (size_t)(bi*NCH + ci*6 + 5)*HW;
  const float* gp = labels  + (size_t)(bi*NCH + ci*6 + 5)*HW;
  const float* mp = tmask   + (size_t)bi*HW;
  int base = blk*4096 + (int)threadIdx.x*4;

  float4 tv0 = *(const float4*)(tp+base);
  float4 tv1 = *(const float4*)(tp+base+1024);
  float4 tv2 = *(const float4*)(tp+base+2048);
  float4 tv3 = *(const float4*)(tp+base+3072);
  float4 gv0 = *(const float4*)(gp+base);
  float4 gv1 = *(const float4*)(gp+base+1024);
  float4 gv2 = *(const float4*)(gp+base+2048);
  float4 gv3 = *(const float4*)(gp+base+3072);
  float4 mv0 = *(const float4*)(mp+base);
  float4 mv1 = *(const float4*)(mp+base+1024);
  float4 mv2 = *(const float4*)(mp+base+2048);
  float4 mv3 = *(const float4*)(mp+base+3072);

  float tt[16]={tv0.x,tv0.y,tv0.z,tv0.w, tv1.x,tv1.y,tv1.z,tv1.w,
                tv2.x,tv2.y,tv2.z,tv2.w, tv3.x,tv3.y,tv3.z,tv3.w};
  float gg[16]={gv0.x,gv0.y,gv0.z,gv0.w, gv1.x,gv1.y,gv1.z,gv1.w,
                gv2.x,gv2.y,gv2.z,gv2.w, gv3.x,gv3.y,gv3.z,gv3.w};
  float mm[16]={mv0.x,mv0.y,mv0.z,mv0.w, mv1.x,mv1.y,mv1.z,mv1.w,
                mv2.x,mv2.y,mv2.z,mv2.w, mv3.x,mv3.y,mv3.z,mv3.w};

  unsigned pos=0, neg=0, mn=0xFFFFFFFFu;
  unsigned char mb[16];
  #pragma unroll
  for (int c=0;c<16;c++){
    bool isneg = (gg[c] <= 0.5f);
    bool tpos  = (mm[c] > 0.5f);
    pos += (unsigned)((!isneg) && tpos);
    neg += (unsigned)isneg;
    mb[c] = (unsigned char)((((tt[c] > 0.0f) && tpos) ? 1u : 0u) |
                            (tpos ? 2u : 0u) | (isneg ? 4u : 0u));
    if (isneg){ unsigned k = flipkey(tt[c]); mn = (k<mn)?k:mn; }
  }
  unsigned char* mw = maskb + (size_t)img*HW + base;
  *(uchar4*)(mw)      = make_uchar4(mb[0],mb[1],mb[2],mb[3]);
  *(uchar4*)(mw+1024) = make_uchar4(mb[4],mb[5],mb[6],mb[7]);
  *(uchar4*)(mw+2048) = make_uchar4(mb[8],mb[9],mb[10],mb[11]);
  *(uchar4*)(mw+3072) = make_uchar4(mb[12],mb[13],mb[14],mb[15]);

  #pragma unroll
  for (int o=32;o;o>>=1){
    pos += __shfl_down(pos,o,64);
    neg += __shfl_down(neg,o,64);
    unsigned om = __shfl_down(mn,o,64); mn = (om<mn)?om:mn;
  }
  __shared__ unsigned sp[4], sn[4], sm[4];
  int wv = threadIdx.x >> 6, ln = threadIdx.x & 63;
  if (ln==0){ sp[wv]=pos; sn[wv]=neg; sm[wv]=mn; }
  __syncthreads();
  if (threadIdx.x==0){
    unsigned m01 = (sm[0]<sm[1])?sm[0]:sm[1];
    unsigned m23 = (sm[2]<sm[3])?sm[2]:sm[3];
    unsigned m = (m01<m23)?m01:m23;
    atomicAdd(&posA[img], sp[0]+sp[1]+sp[2]+sp[3]);
    atomicAdd(&negA[img], sn[0]+sn[1]+sn[2]+sn[3]);
    atomicMax(&maxnkA[img], ~m);
  }
}

// K2: decide per image: fallback / fast min-threshold / generic radix needed
__global__ void k_decide(
    const unsigned* __restrict__ posA, const unsigned* __restrict__ negA,
    const unsigned* __restrict__ maxnkA, unsigned* __restrict__ doneA,
    unsigned* __restrict__ fbA, unsigned* __restrict__ negnumA,
    float* __restrict__ thrA)
{
  int img = threadIdx.x;
  if (img >= 16) return;
  unsigned pos = posA[img], negt = negA[img];
  unsigned p3 = pos*3u;
  unsigned negnum = (p3 < negt) ? p3 : negt;
  if (pos==0u || negnum==0u){
    doneA[img]=1u; fbA[img]=1u; negnumA[img]=1u; thrA[img]=0.0f;
  } else if (negnum == negt){
    doneA[img]=1u; fbA[img]=0u; negnumA[img]=negnum;
    thrA[img] = unflip(~maxnkA[img]);                 // min negative score
  } else {
    doneA[img]=0u; fbA[img]=0u; negnumA[img]=negnum; thrA[img]=0.0f;
  }
}

// ---- generic radix path (early-exits when doneA[img]) ----

// pass-a hist: key[31:21] of negatives
__global__ __launch_bounds__(256) void k_hista(
    const float* __restrict__ outputs, const unsigned char* __restrict__ maskb,
    const unsigned* __restrict__ doneA, unsigned* __restrict__ histA)
{
  int img = blockIdx.x / 50;
  if (doneA[img]) return;
  int blk = blockIdx.x % 50;
  int ci = img>>3, bi = img&7;
  const float* tp = outputs + (size_t)(bi*NCH + ci*6 + 5)*HW;
  const unsigned char* mk = maskb + (size_t)img*HW;
  __shared__ unsigned lh[2048];
  for (int j=threadIdx.x; j<2048; j+=256) lh[j]=0u;
  __syncthreads();
  #pragma unroll
  for (int it=0; it<8; it++){
    int px = blk*8192 + it*1024 + (int)threadIdx.x*4;
    float4 tv = *(const float4*)(tp+px);
    uchar4 mq = *(const uchar4*)(mk+px);
    float tt[4]={tv.x,tv.y,tv.z,tv.w};
    unsigned char ma[4]={mq.x,mq.y,mq.z,mq.w};
    #pragma unroll
    for (int c=0;c<4;c++)
      if (ma[c] & 4) atomicAdd(&lh[flipkey(tt[c]) >> 21], 1u);
  }
  __syncthreads();
  unsigned* gh = histA + (size_t)img*2048u;
  for (int j=threadIdx.x; j<2048; j+=256){
    unsigned v = lh[j];
    if (v) atomicAdd(&gh[j], v);
  }
}

template<int NB>
__device__ void scan_desc(const unsigned* h, unsigned k, unsigned* selOut, unsigned* kremOut)
{
  const int PER = NB/256;
  int t = threadIdx.x;
  unsigned s=0;
  #pragma unroll
  for (int j=0;j<PER;j++) s += h[t*PER+j];
  __shared__ unsigned cs[256];
  cs[t]=s; __syncthreads();
  if (t==0){
    unsigned cum=0, ch=0, kin=k;
    for (int c=255;c>=0;c--){
      if (cum + cs[c] >= k){ ch=(unsigned)c; kin=k-cum; break; }
      cum += cs[c];
    }
    unsigned cum2=0, sel=ch*PER, kr=1;
    for (int x=PER-1;x>=0;x--){
      unsigned v = h[ch*PER+x];
      cum2 += v;
      if (cum2 >= kin){ sel=ch*PER+(unsigned)x; kr = kin - (cum2 - v); break; }
    }
    *selOut = sel; *kremOut = kr;
  }
}

__global__ __launch_bounds__(256) void k_scan_a(
    const unsigned* __restrict__ histA, const unsigned* __restrict__ doneA,
    const unsigned* __restrict__ negnumA, unsigned* __restrict__ sel1A,
    unsigned* __restrict__ krem1A)
{
  int img = blockIdx.x;
  if (doneA[img]) return;
  scan_desc<2048>(histA + (size_t)img*2048u, negnumA[img], &sel1A[img], &krem1A[img]);
}

__global__ __launch_bounds__(256) void k_histb(
    const float* __restrict__ outputs, const unsigned char* __restrict__ maskb,
    const unsigned* __restrict__ sel1A, const unsigned* __restrict__ doneA,
    unsigned* __restrict__ histB)
{
  int img = blockIdx.x / 50;
  if (doneA[img]) return;
  int blk = blockIdx.x % 50;
  int ci = img>>3, bi = img&7;
  unsigned sel1 = sel1A[img];
  const float* tp = outputs + (size_t)(bi*NCH + ci*6 + 5)*HW;
  const unsigned char* mk = maskb + (size_t)img*HW;
  __shared__ unsigned lh[2048];
  for (int j=threadIdx.x; j<2048; j+=256) lh[j]=0u;
  __syncthreads();
  #pragma unroll
  for (int it=0; it<8; it++){
    int px = blk*8192 + it*1024 + (int)threadIdx.x*4;
    float4 tv = *(const float4*)(tp+px);
    uchar4 mq = *(const uchar4*)(mk+px);
    float tt[4]={tv.x,tv.y,tv.z,tv.w};
    unsigned char ma[4]={mq.x,mq.y,mq.z,mq.w};
    #pragma unroll
    for (int c=0;c<4;c++){
      if (ma[c] & 4){
        unsigned key = flipkey(tt[c]);
        if ((key>>21) == sel1) atomicAdd(&lh[(key>>10) & 0x7FFu], 1u);
      }
    }
  }
  __syncthreads();
  unsigned* gh = histB + (size_t)img*2048u;
  for (int j=threadIdx.x; j<2048; j+=256){
    unsigned v = lh[j];
    if (v) atomicAdd(&gh[j], v);
  }
}

__global__ __launch_bounds__(256) void k_scan_b(
    const unsigned* __restrict__ histB, const unsigned* __restrict__ krem1A,
    const unsigned* __restrict__ doneA, unsigned* __restrict__ sel2A,
    unsigned* __restrict__ krem2A)
{
  int img = blockIdx.x;
  if (doneA[img]) return;
  scan_desc<2048>(histB + (size_t)img*2048u, krem1A[img], &sel2A[img], &krem2A[img]);
}

__global__ __launch_bounds__(256) void k_histc(
    const float* __restrict__ outputs, const unsigned char* __restrict__ maskb,
    const unsigned* __restrict__ sel1A, const unsigned* __restrict__ sel2A,
    const unsigned* __restrict__ doneA, unsigned* __restrict__ histC)
{
  int img = blockIdx.x / 50;
  if (doneA[img]) return;
  int blk = blockIdx.x % 50;
  int ci = img>>3, bi = img&7;
  unsigned p22 = (sel1A[img]<<11) | sel2A[img];
  const float* tp = outputs + (size_t)(bi*NCH + ci*6 + 5)*HW;
  const unsigned char* mk = maskb + (size_t)img*HW;
  __shared__ unsigned lh[1024];
  for (int j=threadIdx.x; j<1024; j+=256) lh[j]=0u;
  __syncthreads();
  #pragma unroll
  for (int it=0; it<8; it++){
    int px = blk*8192 + it*1024 + (int)threadIdx.x*4;
    float4 tv = *(const float4*)(tp+px);
    uchar4 mq = *(const uchar4*)(mk+px);
    float tt[4]={tv.x,tv.y,tv.z,tv.w};
    unsigned char ma[4]={mq.x,mq.y,mq.z,mq.w};
    #pragma unroll
    for (int c=0;c<4;c++){
      if (ma[c] & 4){
        unsigned key = flipkey(tt[c]);
        if ((key>>10) == p22) atomicAdd(&lh[key & 0x3FFu], 1u);
      }
    }
  }
  __syncthreads();
  unsigned* gh = histC + (size_t)img*1024u;
  for (int j=threadIdx.x; j<1024; j+=256){
    unsigned v = lh[j];
    if (v) atomicAdd(&gh[j], v);
  }
}

__global__ __launch_bounds__(256) void k_scan_c(
    const unsigned* __restrict__ histC, const unsigned* __restrict__ sel1A,
    const unsigned* __restrict__ sel2A, const unsigned* __restrict__ krem2A,
    const unsigned* __restrict__ doneA, float* __restrict__ thrA)
{
  int img = blockIdx.x;
  if (doneA[img]) return;
  __shared__ unsigned sel3, kr;
  scan_desc<1024>(histC + (size_t)img*1024u, krem2A[img], &sel3, &kr);
  __syncthreads();
  if (threadIdx.x==0){
    unsigned key = (sel1A[img]<<21) | (sel2A[img]<<10) | sel3;
    thrA[img] = unflip(key);
  }
}

// K9: dice sums — 32 elems/thread in two fully-batched halves for MLP
__global__ __launch_bounds__(256) void k_dice(
    const float* __restrict__ outputs, const float* __restrict__ labels,
    const float* __restrict__ tmask, const unsigned char* __restrict__ maskb,
    const unsigned* __restrict__ fbA, const float* __restrict__ thrA,
    float* __restrict__ tacc, float* __restrict__ kacc)
{
  int cimg = blockIdx.x / 50;       // (img)*6 + j
  int blk  = blockIdx.x % 50;
  int img = cimg / 6, j = cimg % 6;
  int ci = img>>3, bi = img&7;
  const float* pp_ = outputs + (size_t)(bi*NCH + ci*6 + j)*HW;
  const float* gp  = labels  + (size_t)(bi*NCH + ci*6 + j)*HW;
  const unsigned char* mk = maskb + (size_t)img*HW;
  const float* tmp = tmask + (size_t)bi*HW;
  bool istext = (j==5);
  bool fb = istext && (fbA[img] != 0u);
  float thr = istext ? thrA[img] : 0.0f;
  float sa=0.f, sb=0.f, sc=0.f;
  #pragma unroll
  for (int half=0; half<2; half++){
    int base = blk*8192 + half*4096 + (int)threadIdx.x*4;
    float4 pv0 = *(const float4*)(pp_+base);
    float4 pv1 = *(const float4*)(pp_+base+1024);
    float4 pv2 = *(const float4*)(pp_+base+2048);
    float4 pv3 = *(const float4*)(pp_+base+3072);
    float4 gv0 = *(const float4*)(gp+base);
    float4 gv1 = *(const float4*)(gp+base+1024);
    float4 gv2 = *(const float4*)(gp+base+2048);
    float4 gv3 = *(const float4*)(gp+base+3072);
    uchar4 mq0 = *(const uchar4*)(mk+base);
    uchar4 mq1 = *(const uchar4*)(mk+base+1024);
    uchar4 mq2 = *(const uchar4*)(mk+base+2048);
    uchar4 mq3 = *(const uchar4*)(mk+base+3072);
    float pa[16]={pv0.x,pv0.y,pv0.z,pv0.w, pv1.x,pv1.y,pv1.z,pv1.w,
                  pv2.x,pv2.y,pv2.z,pv2.w, pv3.x,pv3.y,pv3.z,pv3.w};
    float ga[16]={gv0.x,gv0.y,gv0.z,gv0.w, gv1.x,gv1.y,gv1.z,gv1.w,
                  gv2.x,gv2.y,gv2.z,gv2.w, gv3.x,gv3.y,gv3.z,gv3.w};
    unsigned char ma[16]={mq0.x,mq0.y,mq0.z,mq0.w, mq1.x,mq1.y,mq1.z,mq1.w,
                          mq2.x,mq2.y,mq2.z,mq2.w, mq3.x,mq3.y,mq3.z,mq3.w};
    float ta[16];
    if (fb){
      float4 t0=*(const float4*)(tmp+base),   t1=*(const float4*)(tmp+base+1024);
      float4 t2=*(const float4*)(tmp+base+2048), t3=*(const float4*)(tmp+base+3072);
      ta[0]=t0.x;ta[1]=t0.y;ta[2]=t0.z;ta[3]=t0.w; ta[4]=t1.x;ta[5]=t1.y;ta[6]=t1.z;ta[7]=t1.w;
      ta[8]=t2.x;ta[9]=t2.y;ta[10]=t2.z;ta[11]=t2.w; ta[12]=t3.x;ta[13]=t3.y;ta[14]=t3.z;ta[15]=t3.w;
    }
    #pragma unroll
    for (int c=0;c<16;c++){
      float m;
      if (istext){
        if (fb) m = ta[c];
        else    m = (((pa[c] >= thr) || (ga[c] > 0.5f)) && (ma[c] & 2)) ? 1.0f : 0.0f;
      } else {
        m = (ma[c] & 1) ? 1.0f : 0.0f;
      }
      float p = __fdividef(1.0f, 1.0f + __expf(-pa[c])) * m;
      float tt = ga[c]*m;
      sa += p*tt; sb += p*p; sc += tt*tt;
    }
  }
  #pragma unroll
  for (int o=32;o;o>>=1){
    sa += __shfl_down(sa,o,64); sb += __shfl_down(sb,o,64); sc += __shfl_down(sc,o,64);
  }
  __shared__ float ra[4], rb[4], rc[4];
  int wv = threadIdx.x>>6, ln = threadIdx.x&63;
  if (ln==0){ ra[wv]=sa; rb[wv]=sb; rc[wv]=sc; }
  __syncthreads();
  if (threadIdx.x==0){
    float A=ra[0]+ra[1]+ra[2]+ra[3];
    float Bs=rb[0]+rb[1]+rb[2]+rb[3];
    float Cs=rc[0]+rc[1]+rc[2]+rc[3];
    float* acc = istext ? (tacc + img*3) : (kacc + (img*5 + j)*3);
    atomicAdd(acc+0, A); atomicAdd(acc+1, Bs); atomicAdd(acc+2, Cs);
  }
}

// K10: finalize 3 outputs
__global__ void k_final(const float* __restrict__ tacc, const float* __restrict__ kacc,
                        float* __restrict__ out)
{
  if (blockIdx.x==0 && threadIdx.x==0){
    const float EPSF = 1e-4f;
    float ltA[2], lkA[2];
    for (int i=0;i<2;i++){
      float lt=0.f;
      for (int b=0;b<8;b++){
        int img=i*8+b;
        float a=tacc[img*3], p2=tacc[img*3+1]+EPSF, t2=tacc[img*3+2]+EPSF;
        lt += 1.f - 2.f*a/(p2+t2);
      }
      lt *= 0.125f;
      float lk=0.f;
      for (int b=0;b<8;b++) for (int k=0;k<5;k++){
        int idx=((i*8+b)*5+k)*3;
        float a=kacc[idx], p2=kacc[idx+1]+EPSF, t2=kacc[idx+2]+EPSF;
        lk += 1.f - 2.f*a/(p2+t2);
      }
      lk /= 40.f;
      ltA[i]=lt; lkA[i]=lk;
    }
    float l0 = 0.7f*ltA[0] + 0.3f*lkA[0];
    float l1 = 0.7f*ltA[1] + 0.3f*lkA[1];
    out[0]=0.5f*(l0+l1);
    out[1]=0.5f*(ltA[0]+ltA[1]);
    out[2]=0.5f*(lkA[0]+lkA[1]);
  }
}

extern "C" void kernel_launch(void* const* d_in, const int* in_sizes, int n_in,
                              void* d_out, int out_size, void* d_ws, size_t ws_size,
                              hipStream_t stream)
{
  const float* outputs = (const float*)d_in[0];
  const float* labels  = (const float*)d_in[1];
  const float* tmask   = (const float*)d_in[2];
  float* out = (float*)d_out;
  char* ws = (char*)d_ws;
  float* tacc      = (float*)(ws + OFF_TACC);
  float* kacc      = (float*)(ws + OFF_KACC);
  unsigned* posA   = (unsigned*)(ws + OFF_POS);
  unsigned* negA   = (unsigned*)(ws + OFF_NEG);
  unsigned* doneA  = (unsigned*)(ws + OFF_DONE);
  unsigned* fbA    = (unsigned*)(ws + OFF_FB);
  unsigned* negnumA= (unsigned*)(ws + OFF_NEGNUM);
  unsigned* maxnkA = (unsigned*)(ws + OFF_MAXNK);
  unsigned* sel1A  = (unsigned*)(ws + OFF_SEL1);
  unsigned* krem1A = (unsigned*)(ws + OFF_KREM1);
  unsigned* sel2A  = (unsigned*)(ws + OFF_SEL2);
  unsigned* krem2A = (unsigned*)(ws + OFF_KREM2);
  float* thrA      = (float*)(ws + OFF_THR);
  unsigned* histA  = (unsigned*)(ws + OFF_HA);
  unsigned* histB  = (unsigned*)(ws + OFF_HB);
  unsigned* histC  = (unsigned*)(ws + OFF_HC);
  unsigned char* maskb = (unsigned char*)(ws + OFF_MASK);

  hipMemsetAsync(ws, 0, OFF_META_END, stream);   // accs + meta + hists (~324 KiB)
  k_count <<<1600,256,0,stream>>>(outputs, labels, tmask, maskb, posA, negA, maxnkA);
  k_decide<<<1,64,0,stream>>>(posA, negA, maxnkA, doneA, fbA, negnumA, thrA);
  k_hista <<<800,256,0,stream>>>(outputs, maskb, doneA, histA);
  k_scan_a<<<16,256,0,stream>>>(histA, doneA, negnumA, sel1A, krem1A);
  k_histb <<<800,256,0,stream>>>(outputs, maskb, sel1A, doneA, histB);
  k_scan_b<<<16,256,0,stream>>>(histB, krem1A, doneA, sel2A, krem2A);
  k_histc <<<800,256,0,stream>>>(outputs, maskb, sel1A, sel2A, doneA, histC);
  k_scan_c<<<16,256,0,stream>>>(histC, sel1A, sel2A, krem2A, doneA, thrA);
  k_dice  <<<4800,256,0,stream>>>(outputs, labels, tmask, maskb, fbA, thrA, tacc, kacc);
  k_final <<<1,64,0,stream>>>(tacc, kacc, out);
}